// Round 1
// 292.959 us; speedup vs baseline: 1.1434x; 1.1434x over previous
//
#include <hip/hip_runtime.h>
#include <hip/hip_bf16.h>

// Problem constants (from reference setup_inputs)
static constexpr int NN  = 100000;   // nodes
static constexpr int NE  = 1600000;  // edges
static constexpr int FIN = 128;      // input features
static constexpr int HD  = 64;       // hidden

// Two-level counting sort parameters
static constexpr int NB    = 256;    // coarse buckets
static constexpr int NPB   = 392;    // nodes per bucket (256*392 = 100352 >= NN)
static constexpr int EPB   = NE / NB;   // 6250 edges per hist/binfill block
static constexpr unsigned long long DIV392_MAGIC = 43826197ULL;  // floor(c/392) = (c*M)>>34

typedef __attribute__((ext_vector_type(8))) short bf16x8;
typedef __attribute__((ext_vector_type(4))) float f32x4;

__device__ __forceinline__ float bf2f(unsigned short u) {
    return __uint_as_float(((unsigned int)u) << 16);
}
__device__ __forceinline__ unsigned short f2bf(float f) {
    __hip_bfloat16 hb = __float2bfloat16(f);
    return *(unsigned short*)&hb;
}
__device__ __forceinline__ int bucket_of(int c) {
    return (int)(((unsigned long long)(unsigned int)c * DIV392_MAGIC) >> 34);
}

__device__ __forceinline__ float load_in(const void* p, size_t i, int isbf) {
    return isbf ? bf2f(((const unsigned short*)p)[i]) : ((const float*)p)[i];
}

// ---------- Phase A: histogram over 256 coarse buckets, 4 per-wave LDS copies.
// Block 0 additionally runs the dtype-detect (was a separate 1-block dispatch).
__global__ __launch_bounds__(256) void k_hist(const int* __restrict__ col, int* __restrict__ hist,
                                              const unsigned short* __restrict__ xu,
                                              int* __restrict__ flag) {
    __shared__ int h[4][NB];
    int t = threadIdx.x, w = t >> 6;
#pragma unroll
    for (int r = 0; r < 4; ++r) h[r][t] = 0;
    __syncthreads();
    int base = blockIdx.x * EPB;
    for (int e = base + t; e < base + EPB; e += 256)
        atomicAdd(&h[w][bucket_of(col[e])], 1);
    __syncthreads();
    hist[t * NB + blockIdx.x] = h[0][t] + h[1][t] + h[2][t] + h[3][t];   // hist[bucket][block]
    if (blockIdx.x == 0) {
        __syncthreads();
        int cnt = 0;
        for (int k = t; k < 4096; k += 256) {
            unsigned short u = xu[2 * k];
            int ex = (u >> 7) & 0xFF;
            cnt += (ex >= 110 && ex <= 135) ? 1 : 0;
        }
        h[0][t] = cnt;
        __syncthreads();
        for (int off = 128; off > 0; off >>= 1) {
            if (t < off) h[0][t] += h[0][t + off];
            __syncthreads();
        }
        if (t == 0) flag[0] = (h[0][0] >= 2048) ? 1 : 0;
    }
}

// ---------- Phase B: exclusive scan of 65536 ints (chunk part; bsums kept RAW —
// consumers fold the 64-entry bsums scan locally, removing the k_gscan2 dispatch).
__global__ __launch_bounds__(256) void k_gscan1(int* __restrict__ a, int* __restrict__ bsums) {
    __shared__ int sd[256];
    int t = threadIdx.x;
    int base = blockIdx.x * 1024 + t * 4;
    int v0 = a[base], v1 = a[base + 1], v2 = a[base + 2], v3 = a[base + 3];
    int tsum = v0 + v1 + v2 + v3;
    sd[t] = tsum;
    __syncthreads();
    for (int off = 1; off < 256; off <<= 1) {
        int tmp = (t >= off) ? sd[t - off] : 0;
        __syncthreads();
        sd[t] += tmp;
        __syncthreads();
    }
    int run = sd[t] - tsum;
    a[base] = run; run += v0;
    a[base + 1] = run; run += v1;
    a[base + 2] = run; run += v2;
    a[base + 3] = run;
    if (t == 255) bsums[blockIdx.x] = sd[t];
}

// In-block exclusive scan of the 64 raw bsums into sb[]. All 256 threads hit barriers.
__device__ __forceinline__ void scan_bsums(const int* __restrict__ bsumsRaw, int* sb) {
    int t = threadIdx.x;
    int myv = 0;
    if (t < 64) { myv = bsumsRaw[t]; sb[t] = myv; }
    __syncthreads();
    for (int off = 1; off < 64; off <<= 1) {
        int v = (t < 64 && t >= off) ? sb[t - off] : 0;
        __syncthreads();
        if (t < 64) sb[t] += v;
        __syncthreads();
    }
    if (t < 64) sb[t] -= myv;   // exclusive
    __syncthreads();
}

// ---------- Phase C: scatter packed (row | c_local<<17) into bucket-grouped order.
__global__ __launch_bounds__(256) void k_binfill(const int* __restrict__ row, const int* __restrict__ col,
                                                 const int* __restrict__ histS,
                                                 const int* __restrict__ bsumsRaw,
                                                 int* __restrict__ csr_tmp) {
    __shared__ int cur[NB];
    __shared__ int sb[64];
    int t = threadIdx.x;
    scan_bsums(bsumsRaw, sb);
    cur[t] = histS[t * NB + blockIdx.x] + sb[t >> 2];
    __syncthreads();
    int base = blockIdx.x * EPB;
    for (int e = base + t; e < base + EPB; e += 256) {
        int r = row[e], c = col[e];
        int b = bucket_of(c);
        int p = atomicAdd(&cur[b], 1);
        csr_tmp[p] = r | ((c - b * NPB) << 17);   // r < 2^17, c_local < 392 < 2^9
    }
}

// ---------- Phase D: per-bucket counting sort -> csr_src, start (end offsets), dinv.
__global__ __launch_bounds__(256) void k_bsort(const int* __restrict__ csr_tmp,
                                               const int* __restrict__ histS,
                                               const int* __restrict__ bsumsRaw,
                                               int* __restrict__ csr_src,
                                               int* __restrict__ start,
                                               float* __restrict__ dinv) {
    __shared__ int cnt[512];
    __shared__ int cur[512];
    __shared__ int sb[64];
    int t = threadIdx.x;
    int k = blockIdx.x;
    cnt[t] = 0; cnt[t + 256] = 0;
    scan_bsums(bsumsRaw, sb);
    int S = histS[k * NB] + sb[k >> 2];
    int E = (k < NB - 1) ? (histS[(k + 1) * NB] + sb[(k + 1) >> 2]) : NE;
    int nbase = k * NPB;
    __syncthreads();
    for (int e = S + t; e < E; e += 256)
        atomicAdd(&cnt[csr_tmp[e] >> 17], 1);
    __syncthreads();
    int rc0 = cnt[t], rc1 = cnt[t + 256];
    for (int d = 1; d < 512; d <<= 1) {
        int idx = (t + 1) * (d << 1) - 1;
        if (idx < 512) cnt[idx] += cnt[idx - d];
        __syncthreads();
    }
    if (t == 0) cnt[511] = 0;
    __syncthreads();
    for (int d = 256; d >= 1; d >>= 1) {
        int idx = (t + 1) * (d << 1) - 1;
        if (idx < 512) { int tmp = cnt[idx - d]; cnt[idx - d] = cnt[idx]; cnt[idx] += tmp; }
        __syncthreads();
    }
    int n0 = nbase + t;
    if (n0 < NN) {
        start[n0] = S + cnt[t] + rc0;
        dinv[n0] = rsqrtf((float)(rc0 + 1));
    }
    int li = t + 256;
    int n1 = nbase + li;
    if (li < NPB && n1 < NN) {
        start[n1] = S + cnt[li] + rc1;
        dinv[n1] = rsqrtf((float)(rc1 + 1));
    }
    cur[t] = cnt[t]; cur[t + 256] = cnt[t + 256];
    __syncthreads();
    for (int e = S + t; e < E; e += 256) {
        int u = csr_tmp[e];
        int p = atomicAdd(&cur[u >> 17], 1);
        csr_src[S + p] = u & 0x1FFFF;
    }
}

// ---------- MFMA node GEMM: writes T[n][64] (bf16) = dinv[n] * (X[NN][K] @ W[K][64]).
// Frag layouts (HW-verified): A[m=lane&15][k=quad*8+j], B[k=quad*8+j][n=lane&15],
// D[row=quad*4+r][col=lane&15].
template <int K, bool XDUAL>
__global__ __launch_bounds__(256) void k_gemm_mfma(const void* __restrict__ X,
                                                   const void* __restrict__ W,
                                                   const float* __restrict__ dinv,
                                                   unsigned short* __restrict__ T,
                                                   const int* __restrict__ flag) {
    constexpr int KT = K / 32;
    __shared__ unsigned short Bs[KT * 4 * 64 * 8];  // [kt][nt][lane][8], frag-layout
    int isbf = flag[0];
    for (int tup = threadIdx.x; tup < KT * 4 * 64; tup += 256) {
        int l  = tup & 63;
        int nt = (tup >> 6) & 3;
        int kt = tup >> 8;
        int n  = nt * 16 + (l & 15);
        int kb = kt * 32 + (l >> 4) * 8;
        unsigned short tmp[8];
#pragma unroll
        for (int j = 0; j < 8; ++j) tmp[j] = f2bf(load_in(W, (size_t)(kb + j) * HD + n, isbf));
        *((uint4*)&Bs[(size_t)tup * 8]) = *((const uint4*)tmp);
    }
    __syncthreads();
    int wave = threadIdx.x >> 6, lane = threadIdx.x & 63;
    int quad = lane >> 4, m = lane & 15;
    int row0 = blockIdx.x * 64 + wave * 16;
    int row  = row0 + m;
    int rowc = (row < NN) ? row : (NN - 1);
    bool xf32 = XDUAL && (isbf == 0);
    const char* xrow = (const char*)X + (size_t)rowc * K * (xf32 ? 4 : 2);
    f32x4 acc[4];
#pragma unroll
    for (int nt = 0; nt < 4; ++nt) acc[nt] = (f32x4){0.f, 0.f, 0.f, 0.f};
#pragma unroll
    for (int kt = 0; kt < KT; ++kt) {
        bf16x8 a;
        if (!xf32) {
            a = *((const bf16x8*)(xrow + (size_t)(kt * 32 + quad * 8) * 2));
        } else {
            const float4* fp = (const float4*)(xrow + (size_t)(kt * 32 + quad * 8) * 4);
            float4 u0 = fp[0], u1 = fp[1];
            unsigned short tmp[8] = {f2bf(u0.x), f2bf(u0.y), f2bf(u0.z), f2bf(u0.w),
                                     f2bf(u1.x), f2bf(u1.y), f2bf(u1.z), f2bf(u1.w)};
            a = *((const bf16x8*)tmp);
        }
#pragma unroll
        for (int nt = 0; nt < 4; ++nt) {
            bf16x8 b = *((const bf16x8*)&Bs[(size_t)((kt * 4 + nt) * 64 + lane) * 8]);
            acc[nt] = __builtin_amdgcn_mfma_f32_16x16x32_bf16(a, b, acc[nt], 0, 0, 0);
        }
    }
#pragma unroll
    for (int r = 0; r < 4; ++r) {
        int orow = row0 + quad * 4 + r;
        if (orow < NN) {
            float sc = dinv[orow];
#pragma unroll
            for (int nt = 0; nt < 4; ++nt)
                T[(size_t)orow * 64 + nt * 16 + m] = f2bf(acc[nt][r] * sc);
        }
    }
}

// ---------- fused aggregation core: 32 nodes/block, 8 lanes/node, full 64-feature rows.
// Per edge one coalesced 128B gather (8 lanes x uint4). Result h = relu(d_i*(T_i+sum)+b)
// written bf16 into hS[32][72] (pad 72 shorts -> conflict-free b128 reads in MFMA phase).
__device__ __forceinline__ void agg_to_lds(const unsigned short* __restrict__ T,
                                           const int* __restrict__ endOff,
                                           const int* __restrict__ csr_src,
                                           const float* __restrict__ dinv,
                                           const void* __restrict__ bias, int isbf,
                                           unsigned short (*hS)[72], int i0) {
    int lane = threadIdx.x & 63, wave = threadIdx.x >> 6;
    int g  = lane >> 3;          // node within wave (0..7)
    int fl = (lane & 7) * 8;     // feature base (0..56), 8 feats/lane
    int li = wave * 8 + g;       // node within block (0..31)
    int i  = i0 + li;            // NN % 32 == 0, no bounds needed
    int end = endOff[i];
    int beg = (i == 0) ? 0 : endOff[i - 1];
    union U { uint4 u; unsigned short s[8]; };
    float a[8];
    {
        U t; t.u = *((const uint4*)(T + (size_t)i * 64 + fl));
#pragma unroll
        for (int j = 0; j < 8; ++j) a[j] = bf2f(t.s[j]);
    }
    int k = beg;
    for (; k + 3 < end; k += 4) {
        int s0 = csr_src[k], s1 = csr_src[k + 1], s2 = csr_src[k + 2], s3 = csr_src[k + 3];
        U t0, t1, t2, t3;
        t0.u = *((const uint4*)(T + (size_t)s0 * 64 + fl));
        t1.u = *((const uint4*)(T + (size_t)s1 * 64 + fl));
        t2.u = *((const uint4*)(T + (size_t)s2 * 64 + fl));
        t3.u = *((const uint4*)(T + (size_t)s3 * 64 + fl));
#pragma unroll
        for (int j = 0; j < 8; ++j)
            a[j] += bf2f(t0.s[j]) + bf2f(t1.s[j]) + bf2f(t2.s[j]) + bf2f(t3.s[j]);
    }
    for (; k < end; ++k) {
        int s = csr_src[k];
        U t; t.u = *((const uint4*)(T + (size_t)s * 64 + fl));
#pragma unroll
        for (int j = 0; j < 8; ++j) a[j] += bf2f(t.s[j]);
    }
    float di = dinv[i];
    U o;
#pragma unroll
    for (int j = 0; j < 8; ++j)
        o.s[j] = f2bf(fmaxf(fmaf(di, a[j], load_in(bias, fl + j, isbf)), 0.f));
    *((uint4*)&hS[li][fl]) = o.u;
}

// ---------- fused: aggregate conv-k input T -> h (LDS) -> h @ W2 -> dinv-scale -> Tb.
// Replaces {2x k_agg_half + k_gemm_mfma<HD>} and the bufH round trip.
__global__ __launch_bounds__(256) void k_agg_gemm(const unsigned short* __restrict__ T,
                                                  const int* __restrict__ endOff,
                                                  const int* __restrict__ csr_src,
                                                  const float* __restrict__ dinv,
                                                  const void* __restrict__ bias,
                                                  const void* __restrict__ W2,
                                                  const int* __restrict__ flag,
                                                  unsigned short* __restrict__ Tb) {
    __shared__ unsigned short hS[32][72];
    __shared__ unsigned short Bs[2 * 4 * 64 * 8];   // W2 frags, 8 KB
    int isbf = flag[0];
    for (int tup = threadIdx.x; tup < 512; tup += 256) {
        int l  = tup & 63;
        int nt = (tup >> 6) & 3;
        int kt = tup >> 8;
        int n  = nt * 16 + (l & 15);
        int kb = kt * 32 + (l >> 4) * 8;
        unsigned short tmp[8];
#pragma unroll
        for (int j = 0; j < 8; ++j) tmp[j] = f2bf(load_in(W2, (size_t)(kb + j) * HD + n, isbf));
        *((uint4*)&Bs[(size_t)tup * 8]) = *((const uint4*)tmp);
    }
    int i0 = blockIdx.x * 32;
    agg_to_lds(T, endOff, csr_src, dinv, bias, isbf, hS, i0);
    __syncthreads();   // covers hS and Bs
    int wave = threadIdx.x >> 6, lane = threadIdx.x & 63;
    int quad = lane >> 4, m = lane & 15;
    int tile = wave >> 1;            // 2 row-tiles of 16 nodes
    int nb   = (wave & 1) * 2;       // 2 col-tiles of 16 per wave
    f32x4 acc0 = (f32x4){0.f, 0.f, 0.f, 0.f};
    f32x4 acc1 = (f32x4){0.f, 0.f, 0.f, 0.f};
#pragma unroll
    for (int kt = 0; kt < 2; ++kt) {
        bf16x8 a  = *((const bf16x8*)&hS[tile * 16 + m][kt * 32 + quad * 8]);
        bf16x8 b0 = *((const bf16x8*)&Bs[(size_t)((kt * 4 + nb) * 64 + lane) * 8]);
        bf16x8 b1 = *((const bf16x8*)&Bs[(size_t)((kt * 4 + nb + 1) * 64 + lane) * 8]);
        acc0 = __builtin_amdgcn_mfma_f32_16x16x32_bf16(a, b0, acc0, 0, 0, 0);
        acc1 = __builtin_amdgcn_mfma_f32_16x16x32_bf16(a, b1, acc1, 0, 0, 0);
    }
#pragma unroll
    for (int r = 0; r < 4; ++r) {
        int orow = i0 + tile * 16 + quad * 4 + r;
        float sc = dinv[orow];
        Tb[(size_t)orow * 64 + nb * 16 + m]       = f2bf(acc0[r] * sc);
        Tb[(size_t)orow * 64 + (nb + 1) * 16 + m] = f2bf(acc1[r] * sc);
    }
}

// ---------- fused: aggregate conv2 -> h2 (LDS) -> h2 @ Wl(packed 16 cols) -> P[n][16].
// Replaces {2x k_agg_half + k_pgemm} and the second bufH round trip.
__global__ __launch_bounds__(256) void k_agg_pgemm(const unsigned short* __restrict__ T,
                                                   const int* __restrict__ endOff,
                                                   const int* __restrict__ csr_src,
                                                   const float* __restrict__ dinv,
                                                   const void* __restrict__ bias,
                                                   const void* __restrict__ Wl,
                                                   const void* __restrict__ bl,
                                                   const int* __restrict__ flag,
                                                   unsigned short* __restrict__ P) {
    __shared__ unsigned short hS[32][72];
    int isbf = flag[0];
    int lane = threadIdx.x & 63;
    int quad = lane >> 4, m = lane & 15;
    bf16x8 bfr[2];
#pragma unroll
    for (int kt = 0; kt < 2; ++kt) {
        unsigned short tmp[8];
#pragma unroll
        for (int j = 0; j < 8; ++j) {
            int kk = kt * 32 + quad * 8 + j;
            float w = (m < 8) ? load_in(Wl, (size_t)kk * 8 + m, isbf)
                              : load_in(Wl, (size_t)(64 + kk) * 8 + (m - 8), isbf);
            tmp[j] = f2bf(w);
        }
        bfr[kt] = *((const bf16x8*)tmp);
    }
    float binit = (m < 8) ? load_in(bl, m, isbf) : 0.f;
    int i0 = blockIdx.x * 32;
    agg_to_lds(T, endOff, csr_src, dinv, bias, isbf, hS, i0);
    __syncthreads();
    int wave = threadIdx.x >> 6;
    if (wave < 2) {   // 2 row-tiles of 16 nodes; N=16 packed output
        f32x4 acc = (f32x4){binit, binit, binit, binit};
#pragma unroll
        for (int kt = 0; kt < 2; ++kt) {
            bf16x8 a = *((const bf16x8*)&hS[wave * 16 + m][kt * 32 + quad * 8]);
            acc = __builtin_amdgcn_mfma_f32_16x16x32_bf16(a, bfr[kt], acc, 0, 0, 0);
        }
#pragma unroll
        for (int r = 0; r < 4; ++r) {
            int orow = i0 + wave * 16 + quad * 4 + r;
            P[(size_t)orow * 16 + m] = f2bf(acc[r]);
        }
    }
}

// ---------- edge output: out[e] = P[row[e]][0:8] + P[col[e]][8:16]  (bl already in P)
__global__ __launch_bounds__(256) void k_edge_add(const unsigned short* __restrict__ P,
                                                  const int* __restrict__ erow,
                                                  const int* __restrict__ ecol,
                                                  void* __restrict__ out,
                                                  const int* __restrict__ flag) {
    int isbf = flag[0];
    int e = blockIdx.x * 256 + threadIdx.x;   // NE % 256 == 0
    int i = erow[e], j = ecol[e];
    ushort4 r0 = *((const ushort4*)(P + (size_t)i * 16));
    ushort4 r1 = *((const ushort4*)(P + (size_t)i * 16 + 4));
    ushort4 c0 = *((const ushort4*)(P + (size_t)j * 16 + 8));
    ushort4 c1 = *((const ushort4*)(P + (size_t)j * 16 + 12));
    float v[8] = {bf2f(r0.x) + bf2f(c0.x), bf2f(r0.y) + bf2f(c0.y),
                  bf2f(r0.z) + bf2f(c0.z), bf2f(r0.w) + bf2f(c0.w),
                  bf2f(r1.x) + bf2f(c1.x), bf2f(r1.y) + bf2f(c1.y),
                  bf2f(r1.z) + bf2f(c1.z), bf2f(r1.w) + bf2f(c1.w)};
    if (isbf) {
        union { unsigned short h[8]; uint4 u; } p;
#pragma unroll
        for (int o = 0; o < 8; ++o) p.h[o] = f2bf(v[o]);
        *((uint4*)((__hip_bfloat16*)out + (size_t)e * 8)) = p.u;
    } else {
        float* op = (float*)out + (size_t)e * 8;
        ((float4*)op)[0] = make_float4(v[0], v[1], v[2], v[3]);
        ((float4*)op)[1] = make_float4(v[4], v[5], v[6], v[7]);
    }
}

extern "C" void kernel_launch(void* const* d_in, const int* in_sizes, int n_in,
                              void* d_out, int out_size, void* d_ws, size_t ws_size,
                              hipStream_t stream) {
    const void* x  = d_in[0];
    const int*  ei = (const int*)d_in[1];
    const void* W1 = d_in[2];
    const void* b1 = d_in[3];
    const void* W2 = d_in[4];
    const void* b2 = d_in[5];
    const void* Wl = d_in[6];
    const void* bl = d_in[7];
    const int* row = ei;
    const int* col = ei + NE;

    char* ws = (char*)d_ws;
    int*   flag    = (int*)ws;    ws += 16;
    int*   hist    = (int*)ws;    ws += (size_t)NB * NB * 4;   // 256 KB, scanned in place
    int*   bsums   = (int*)ws;    ws += 256 * 4;
    int*   start   = (int*)ws;    ws += (size_t)NN * 4;        // end offsets per node
    float* dinv    = (float*)ws;  ws += (size_t)NN * 4;
    int*   csr_tmp = (int*)ws;    ws += (size_t)NE * 4;
    int*   csr_src = (int*)ws;    ws += (size_t)NE * 4;
    unsigned short* T  = (unsigned short*)ws;  ws += (size_t)NN * 64 * 2;  // 12.8 MB
    unsigned short* Tb = (unsigned short*)ws;  ws += (size_t)NN * 64 * 2;  // 12.8 MB
    unsigned short* P  = (unsigned short*)ws;                              // 3.2 MB

    int gE   = (NE + 255) / 256;
    int gN32 = NN / 32;               // fused agg kernels: 32 nodes/block (NN%32==0)
    int gN64 = (NN + 63) / 64;        // mfma gemm: 64 rows/block

    // CSR build: histogram(+detect) -> chunk scan -> packed bin scatter -> bucket sort
    k_hist   <<<NB, 256, 0, stream>>>(col, hist, (const unsigned short*)x, flag);
    k_gscan1 <<<64, 256, 0, stream>>>(hist, bsums);
    k_binfill<<<NB, 256, 0, stream>>>(row, col, hist, bsums, csr_tmp);
    k_bsort  <<<NB, 256, 0, stream>>>(csr_tmp, hist, bsums, csr_src, start, dinv);

    // conv1 GEMM: T = dinv * (x @ W1), full 64-feature rows
    k_gemm_mfma<FIN, true><<<gN64, 256, 0, stream>>>(x, W1, dinv, T, flag);

    // conv1 agg + relu + conv2 GEMM fused: Tb = dinv * (relu(d*(agg T)+b1) @ W2)
    k_agg_gemm <<<gN32, 256, 0, stream>>>(T, start, csr_src, dinv, b1, W2, flag, Tb);

    // conv2 agg + relu + edge-projection GEMM fused: P = relu(d*(agg Tb)+b2) @ Wl (+bl)
    k_agg_pgemm<<<gN32, 256, 0, stream>>>(Tb, start, csr_src, dinv, b2, Wl, bl, flag, P);

    // edge head: gather-add from L2-resident P
    k_edge_add <<<gE, 256, 0, stream>>>(P, row, col, d_out, flag);
}